// Round 1
// baseline (245.978 us; speedup 1.0000x reference)
//
#include <hip/hip_runtime.h>
#include <math.h>

#define NGRAPH 1000
#define NPG    100    // nodes per graph
#define EPG    1600   // edges per graph
#define NF     32
#define NC     10
#define KP     30
#define OUTL   16
#define INL    97
#define NITER  3
#define NT     512

struct SMem {
  float feat[NPG * INL];                 // 38800 B : x1|x2|x3|x4 per node
  union {
    struct {
      float x0[NPG * NF];                // 12800 B : raw input features
      unsigned short epack[EPG];         // 3200 B  : packed (src<<8|dst)
    } a;
    float priors[KP * NC * OUTL];        // 19200 B : capsule priors
  } u;
  union {
    float h[NPG * NF];                   // 12800 B : per-layer x@W
    float wc[OUTL * INL];                // 6208 B  : one class of Wcap
  } v;
  float W[NF * NF];                      // 4096 B
  float bias2[2][NF];                    // 256 B (double-buffered bias)
  unsigned char csr[EPG];                // 1600 B : src local ids grouped by dst
  int ptr[NPG + 1];                      // 404 B
  int cnt[NPG];                          // 400 B (counts, then fill cursors)
  float dinv[NPG];                       // 400 B
  int order[KP];                         // 120 B
  float prsq[KP * NC];                   // 1200 B
  float simbuf[KP * NC];                 // 1200 B (sim -> probs in place)
  float outv[NC * OUTL];                 // 640 B
  float osq[NC];                         // 40 B
  float smax[NC];                        // 40 B
  float ssum[NC];                        // 40 B
};                                       // total ~81.2 KB -> 2 blocks/CU

__global__ __launch_bounds__(NT, 4) void gcn_caps_kernel(
    const float* __restrict__ x,
    const int* __restrict__ esrc,
    const int* __restrict__ edst,
    const float* __restrict__ W1, const float* __restrict__ b1,
    const float* __restrict__ W2, const float* __restrict__ b2,
    const float* __restrict__ W3, const float* __restrict__ b3,
    const float* __restrict__ W4, const float* __restrict__ b4,
    const float* __restrict__ Wcap,
    float* __restrict__ out)
{
  extern __shared__ char smem_raw[];
  SMem& s = *reinterpret_cast<SMem*>(smem_raw);
  const int g = blockIdx.x;
  const int tid = threadIdx.x;

  // ---- Phase 1: load node features (contiguous, coalesced) + zero counters
  const float* xg = x + (size_t)g * NPG * NF;
  for (int i = tid; i < NPG * NF; i += NT) s.u.a.x0[i] = xg[i];
  for (int i = tid; i < NPG; i += NT) s.cnt[i] = 0;
  __syncthreads();

  // ---- Phase 2: read this graph's edges (global idx g + k*NGRAPH), pack, count degree
  for (int k = tid; k < EPG; k += NT) {
    int si = esrc[g + k * NGRAPH] - g * NPG;
    int di = edst[g + k * NGRAPH] - g * NPG;
    s.u.a.epack[k] = (unsigned short)((si << 8) | di);
    atomicAdd(&s.cnt[di], 1);
  }
  __syncthreads();

  // ---- Phase 3: exclusive prefix sum over 100 counts (serial, tiny) ; dinv
  if (tid == 0) {
    int run = 0;
    for (int d = 0; d < NPG; ++d) { s.ptr[d] = run; run += s.cnt[d]; }
    s.ptr[NPG] = run;
  }
  __syncthreads();
  for (int d = tid; d < NPG; d += NT) {
    s.dinv[d] = rsqrtf((float)s.cnt[d] + 1.0f);  // deg = in-count + 1
    s.cnt[d] = s.ptr[d];                          // becomes fill cursor
  }
  __syncthreads();

  // ---- Phase 4: fill CSR (src ids grouped by dst)
  for (int k = tid; k < EPG; k += NT) {
    int pk = s.u.a.epack[k];
    int di = pk & 0xFF;
    int pos = atomicAdd(&s.cnt[di], 1);
    s.csr[pos] = (unsigned char)(pk >> 8);
  }
  // ---- Phase 5: load W1/b1
  for (int i = tid; i < NF * NF; i += NT) s.W[i] = W1[i];
  if (tid < NF) s.bias2[0][tid] = b1[tid];
  __syncthreads();

  // ---- Phase 6: four GCN layers, all in LDS
  for (int l = 0; l < 4; ++l) {
    const int OUTF = (l < 3) ? NF : 1;
    // GEMM: h = in @ W   (in = x0 for l=0, else previous layer's feat columns)
    if (OUTF == NF) {
      for (int o = tid; o < NPG * NF; o += NT) {
        int node = o >> 5, c = o & 31;
        const float* inr = (l == 0) ? &s.u.a.x0[node * NF]
                                    : &s.feat[node * INL + (l - 1) * NF];
        float a = 0.f;
        #pragma unroll
        for (int k = 0; k < NF; ++k) a += inr[k] * s.W[k * NF + c];
        s.v.h[o] = a;
      }
    } else {
      for (int node = tid; node < NPG; node += NT) {
        const float* inr = &s.feat[node * INL + 2 * NF];
        float a = 0.f;
        #pragma unroll
        for (int k = 0; k < NF; ++k) a += inr[k] * s.W[k];
        s.v.h[node] = a;
      }
    }
    __syncthreads();

    // prefetch next layer's weights (s.W dead for rest of this layer; overlaps aggregation)
    if (l == 0) {
      for (int i = tid; i < NF * NF; i += NT) s.W[i] = W2[i];
      if (tid < NF) s.bias2[1][tid] = b2[tid];
    } else if (l == 1) {
      for (int i = tid; i < NF * NF; i += NT) s.W[i] = W3[i];
      if (tid < NF) s.bias2[0][tid] = b3[tid];
    } else if (l == 2) {
      if (tid < NF) s.W[tid] = W4[tid];
      if (tid == 0) s.bias2[1][0] = b4[0];
    }

    // Aggregation: out[d] = dinv[d]*sum_{e->d} h[src]*dinv[src] + h[d]*dinv[d]^2 + b ; tanh
    const float* bcur = s.bias2[l & 1];
    if (OUTF == NF) {
      int grp = tid >> 5, ln = tid & 31;
      for (int d = grp; d < NPG; d += NT / 32) {
        int p0 = s.ptr[d], p1 = s.ptr[d + 1];
        float r = 0.f;
        for (int idx = p0; idx < p1; ++idx) {
          int sc = s.csr[idx];
          r += s.v.h[sc * NF + ln] * s.dinv[sc];
        }
        float di = s.dinv[d];
        float val = di * r + s.v.h[d * NF + ln] * di * di + bcur[ln];
        s.feat[d * INL + l * NF + ln] = tanhf(val);
      }
    } else {
      for (int d = tid; d < NPG; d += NT) {
        int p0 = s.ptr[d], p1 = s.ptr[d + 1];
        float r = 0.f;
        for (int idx = p0; idx < p1; ++idx) {
          int sc = s.csr[idx];
          r += s.v.h[sc] * s.dinv[sc];
        }
        float di = s.dinv[d];
        s.feat[d * INL + 3 * NF] = tanhf(di * r + s.v.h[d] * di * di + bcur[0]);
      }
    }
    __syncthreads();
  }

  // ---- Phase 7: stable top-30 by feat[:,96] descending (rank = #greater + #equal-with-smaller-idx)
  if (tid < NPG) {
    float vv = s.feat[tid * INL + (INL - 1)];
    int rank = 0;
    for (int j = 0; j < NPG; ++j) {
      float vj = s.feat[j * INL + (INL - 1)];
      rank += (vj > vv) || (vj == vv && j < tid);
    }
    if (rank < KP) s.order[rank] = tid;
  }
  __syncthreads();

  // ---- Phase 8: priors[i][c][e] = sum_l pooled[i][l] * Wcap[c][e][l], staged per class
  for (int c = 0; c < NC; ++c) {
    for (int i = tid; i < OUTL * INL; i += NT) s.v.wc[i] = Wcap[c * OUTL * INL + i];
    __syncthreads();
    if (tid < KP * OUTL) {
      int i = tid >> 4, e = tid & 15;
      const float* fr = &s.feat[s.order[i] * INL];
      const float* wr = &s.v.wc[e * INL];
      float a = 0.f;
      for (int l = 0; l < INL; ++l) a += fr[l] * wr[l];
      s.u.priors[(i * NC + c) * OUTL + e] = a;
    }
    __syncthreads();
  }

  // ---- Phase 9: pr_sq and out init (mean over i)
  if (tid < KP * NC) {
    int i = tid / NC, c = tid % NC;
    float a = 0.f;
    for (int e = 0; e < OUTL; ++e) {
      float p = s.u.priors[(i * NC + c) * OUTL + e];
      a += p * p;
    }
    s.prsq[tid] = a;
  }
  if (tid < NC * OUTL) {
    int c = tid >> 4, e = tid & 15;
    float a = 0.f;
    for (int i = 0; i < KP; ++i) a += s.u.priors[(i * NC + c) * OUTL + e];
    s.outv[tid] = a * (1.0f / KP);
  }
  __syncthreads();

  // ---- Phase 10: routing iterations
  for (int it = 0; it < NITER; ++it) {
    if (tid < NC) {
      float a = 0.f;
      for (int e = 0; e < OUTL; ++e) { float o = s.outv[tid * OUTL + e]; a += o * o; }
      s.osq[tid] = a;
    }
    __syncthreads();
    if (tid < KP * NC) {
      int i = tid / NC, c = tid % NC;
      float xy = 0.f;
      for (int e = 0; e < OUTL; ++e)
        xy += s.u.priors[(i * NC + c) * OUTL + e] * s.outv[c * OUTL + e];
      float den = s.prsq[tid] + s.osq[c] - xy;
      s.simbuf[tid] = xy / den;
    }
    __syncthreads();
    if (tid < NC) {
      float m = -1e30f;
      for (int i = 0; i < KP; ++i) m = fmaxf(m, s.simbuf[i * NC + tid]);
      float ss = 0.f;
      for (int i = 0; i < KP; ++i) ss += expf(s.simbuf[i * NC + tid] - m);
      s.smax[tid] = m;
      s.ssum[tid] = ss;
    }
    __syncthreads();
    if (tid < KP * NC) {
      int c = tid % NC;
      s.simbuf[tid] = expf(s.simbuf[tid] - s.smax[c]) / s.ssum[c];  // probs
    }
    __syncthreads();
    if (tid < NC * OUTL) {
      int c = tid >> 4, e = tid & 15;
      float a = 0.f;
      for (int i = 0; i < KP; ++i)
        a += s.simbuf[i * NC + c] * s.u.priors[(i * NC + c) * OUTL + e];
      s.outv[tid] = a;
    }
    __syncthreads();
  }

  // ---- Phase 11: classes = ||out||_2 per class
  if (tid < NC) {
    float a = 0.f;
    for (int e = 0; e < OUTL; ++e) { float o = s.outv[tid * OUTL + e]; a += o * o; }
    out[(size_t)g * NC + tid] = sqrtf(a);
  }
}

extern "C" void kernel_launch(void* const* d_in, const int* in_sizes, int n_in,
                              void* d_out, int out_size, void* d_ws, size_t ws_size,
                              hipStream_t stream) {
  const float* x    = (const float*)d_in[0];
  const int*   esrc = (const int*)d_in[1];
  const int*   edst = (const int*)d_in[2];
  // d_in[3] = batch (unused; implicit by construction)
  const float* W1 = (const float*)d_in[4];
  const float* b1 = (const float*)d_in[5];
  const float* W2 = (const float*)d_in[6];
  const float* b2 = (const float*)d_in[7];
  const float* W3 = (const float*)d_in[8];
  const float* b3 = (const float*)d_in[9];
  const float* W4 = (const float*)d_in[10];
  const float* b4 = (const float*)d_in[11];
  const float* Wcap = (const float*)d_in[12];
  float* outp = (float*)d_out;

  // >64KB dynamic LDS needs the attribute bump (idempotent, not a stream op)
  (void)hipFuncSetAttribute((const void*)gcn_caps_kernel,
                            hipFuncAttributeMaxDynamicSharedMemorySize,
                            (int)sizeof(SMem));
  gcn_caps_kernel<<<NGRAPH, NT, sizeof(SMem), stream>>>(
      x, esrc, edst, W1, b1, W2, b2, W3, b3, W4, b4, Wcap, outp);
}

// Round 2
// 135.785 us; speedup vs baseline: 1.8115x; 1.8115x over previous
//
#include <hip/hip_runtime.h>
#include <math.h>

#define NGRAPH 1000
#define NPG    100
#define EPG    1600
#define NF     32
#define NC     10
#define KP     30
#define OUTL   16
#define INL    97
#define NITER  3
#define NT     512

#define FSTR   100   // feat row stride (floats): 4 mod 32 banks, 16B aligned
#define HSTR   36    // hs row stride: 4 mod 32 banks, 16B aligned
#define LQ     24    // 24 quads cover l=0..95; l=96 handled as scalar

#define WS_EDGES_BYTES ((size_t)NGRAPH * EPG * 4)        // 6,400,000
#define WS_CAPT_FLOATS (NC * LQ * OUTL * 4)              // 15,360
#define WS_CAPL_FLOATS (NC * OUTL)                       // 160
#define WS_CAP_BYTES   ((size_t)(WS_CAPT_FLOATS + WS_CAPL_FLOATS) * 4)

struct SMem {
  float feat[NPG * FSTR];                    // 40000 : x1|x2|x3 cols 0..95, x4 col 96
  union {
    unsigned short epack[EPG];               // 3200 : (src<<8|dst), dead after CSR fill
    float priors[KP * NC * OUTL];            // 19200
  } u;
  union {
    float hs[NPG * HSTR];                    // 14400 : h*dinv per layer (dead after layer 3)
    struct {
      float prsq[KP * NC];                   // 1200
      float simbuf[KP * NC];                 // 1200
      float outv[NC * OUTL];                 // 640
      float osq[NC];                         // 40 (unused slot kept for alignment)
      float smax[NC];                        // 40
      float ssum[NC];                        // 40 (stores 1/sum)
      int   order[KP];                       // 120
    } r;
  } v;
  float W[NF * NF];                          // 4096
  float bias2[2][NF];                        // 256
  unsigned char csr[EPG];                    // 1600
  int ptr[NPG + 1];                          // 404
  int cnt[NPG];                              // 400
  float dinv[NPG];                           // 400
};                                           // 80756 B -> 2 blocks/CU

__device__ __forceinline__ float4 ld4(const float* p) { return *reinterpret_cast<const float4*>(p); }
__device__ __forceinline__ void st4(float* p, float4 v) { *reinterpret_cast<float4*>(p) = v; }
__device__ __forceinline__ float dot4(float4 a, float4 b) { return a.x*b.x + a.y*b.y + a.z*b.z + a.w*b.w; }
__device__ __forceinline__ float tanh_fast(float x) {
  float e = __expf(2.f * x);                 // inf for large x -> result 1.0 (correct)
  return 1.f - 2.f / (e + 1.f);
}

// ---- pre-kernel 1: transpose edges [k][g] -> [g][k], pack local (src<<8|dst)
__global__ void prek_edges(const int* __restrict__ esrc, const int* __restrict__ edst,
                           unsigned int* __restrict__ wsE) {
  __shared__ unsigned int t[64][65];
  const int kb = blockIdx.x % (EPG / 64);    // 25
  const int gb = blockIdx.x / (EPG / 64);    // 16 (ceil(1000/64))
  const int lane = threadIdx.x & 63;
  const int row  = threadIdx.x >> 6;         // 0..3
  #pragma unroll
  for (int r = row; r < 64; r += 4) {
    int k = kb * 64 + r;
    int g = gb * 64 + lane;
    if (g < NGRAPH) {
      int idx = k * NGRAPH + g;
      int si = esrc[idx] - g * NPG;
      int di = edst[idx] - g * NPG;
      t[r][lane] = (unsigned int)((si << 8) | di);
    }
  }
  __syncthreads();
  #pragma unroll
  for (int r = row; r < 64; r += 4) {
    int g = gb * 64 + r;
    int k = kb * 64 + lane;
    if (g < NGRAPH) wsE[(size_t)g * EPG + k] = t[lane][r];
  }
}

// ---- pre-kernel 2: Wcap[c][e][l] -> capT[c][lq][e][4] (zero-padded) + capL[c][e] (l=96)
__global__ void prek_cap(const float* __restrict__ Wcap, float* __restrict__ capT,
                         float* __restrict__ capL) {
  int o = blockIdx.x * 256 + threadIdx.x;
  if (o < WS_CAPT_FLOATS) {
    int j  = o & 3;
    int e  = (o >> 2) & 15;
    int lq = (o >> 6) % LQ;
    int c  = (o >> 6) / LQ;
    capT[o] = Wcap[(c * OUTL + e) * INL + lq * 4 + j];   // lq*4+j <= 95
  }
  if (o < WS_CAPL_FLOATS) capL[o] = Wcap[o * INL + 96];
}

template <bool WSE, bool WSC>
__global__ __launch_bounds__(NT, 4) void gcn_caps(
    const float* __restrict__ x,
    const int* __restrict__ esrc, const int* __restrict__ edst,
    const float* __restrict__ W1, const float* __restrict__ b1,
    const float* __restrict__ W2, const float* __restrict__ b2,
    const float* __restrict__ W3, const float* __restrict__ b3,
    const float* __restrict__ W4, const float* __restrict__ b4,
    const float* __restrict__ Wcap,
    const unsigned int* __restrict__ wsE,
    const float* __restrict__ capT, const float* __restrict__ capL,
    float* __restrict__ out)
{
  extern __shared__ char smem_raw[];
  SMem& s = *reinterpret_cast<SMem*>(smem_raw);
  const int g = blockIdx.x;
  const int tid = threadIdx.x;

  // ---- P1: zero counters, stage W1/b1
  for (int i = tid; i < NPG; i += NT) s.cnt[i] = 0;
  for (int i = tid; i < NF * NF; i += NT) s.W[i] = W1[i];
  if (tid < NF) s.bias2[0][tid] = b1[tid];
  __syncthreads();

  // ---- P2: edges -> epack + degree count
  if (WSE) {
    const uint4* ep4 = reinterpret_cast<const uint4*>(wsE + (size_t)g * EPG);
    for (int q = tid; q < EPG / 4; q += NT) {
      uint4 p = ep4[q];
      unsigned int lo = (p.x & 0xFFFFu) | (p.y << 16);
      unsigned int hi = (p.z & 0xFFFFu) | (p.w << 16);
      reinterpret_cast<uint2*>(s.u.epack)[q] = make_uint2(lo, hi);
      atomicAdd(&s.cnt[p.x & 0xFF], 1);
      atomicAdd(&s.cnt[p.y & 0xFF], 1);
      atomicAdd(&s.cnt[p.z & 0xFF], 1);
      atomicAdd(&s.cnt[p.w & 0xFF], 1);
    }
  } else {
    for (int k = tid; k < EPG; k += NT) {
      int si = esrc[g + k * NGRAPH] - g * NPG;
      int di = edst[g + k * NGRAPH] - g * NPG;
      s.u.epack[k] = (unsigned short)((si << 8) | di);
      atomicAdd(&s.cnt[di], 1);
    }
  }
  __syncthreads();

  // ---- P3: wave-parallel exclusive scan (2 elems per lane)
  if (tid < 64) {
    int j = tid;
    int a0 = (2 * j < NPG) ? s.cnt[2 * j] : 0;
    int a1 = (2 * j + 1 < NPG) ? s.cnt[2 * j + 1] : 0;
    int t = a0 + a1;
    int run = t;
    #pragma unroll
    for (int off = 1; off < 64; off <<= 1) {
      int u = __shfl_up(run, off);
      if (j >= off) run += u;
    }
    int excl = run - t;
    if (2 * j < NPG) s.ptr[2 * j] = excl;
    if (2 * j + 1 < NPG) s.ptr[2 * j + 1] = excl + a0;
    if (j == 63) s.ptr[NPG] = run;
  }
  __syncthreads();
  for (int d = tid; d < NPG; d += NT) {
    s.dinv[d] = rsqrtf((float)s.cnt[d] + 1.0f);
    s.cnt[d] = s.ptr[d];                      // becomes fill cursor
  }
  __syncthreads();

  // ---- P4: CSR fill
  for (int k = tid; k < EPG; k += NT) {
    int pk = s.u.epack[k];
    int pos = atomicAdd(&s.cnt[pk & 0xFF], 1);
    s.csr[pos] = (unsigned char)(pk >> 8);
  }
  __syncthreads();

  // ---- P6: three 32-wide GCN layers
  const float4* xr = reinterpret_cast<const float4*>(x + (size_t)g * NPG * NF);
  for (int l = 0; l < 3; ++l) {
    // GEMM: hs[node][c] = (in[node] @ W)[c] * dinv[node]; thread = (node, c-quad)
    {
      int nd = tid >> 3, cq = tid & 7;
      #pragma unroll
      for (int pass = 0; pass < 2; ++pass) {
        int node = nd + pass * 64;
        if (node < NPG) {
          float4 acc = make_float4(0.f, 0.f, 0.f, 0.f);
          #pragma unroll
          for (int kq = 0; kq < 8; ++kq) {
            float4 a4 = (l == 0) ? xr[node * 8 + kq]
                                 : ld4(&s.feat[node * FSTR + (l - 1) * NF + kq * 4]);
            const float av[4] = {a4.x, a4.y, a4.z, a4.w};
            #pragma unroll
            for (int j = 0; j < 4; ++j) {
              float4 w4 = ld4(&s.W[(kq * 4 + j) * NF + cq * 4]);
              acc.x += av[j] * w4.x; acc.y += av[j] * w4.y;
              acc.z += av[j] * w4.z; acc.w += av[j] * w4.w;
            }
          }
          float di = s.dinv[node];
          acc.x *= di; acc.y *= di; acc.z *= di; acc.w *= di;
          st4(&s.v.hs[node * HSTR + cq * 4], acc);
        }
      }
    }
    __syncthreads();

    // prefetch next weights (overlaps aggregation; agg never reads W)
    if (l == 0) {
      for (int i = tid; i < NF * NF; i += NT) s.W[i] = W2[i];
      if (tid < NF) s.bias2[1][tid] = b2[tid];
    } else if (l == 1) {
      for (int i = tid; i < NF * NF; i += NT) s.W[i] = W3[i];
      if (tid < NF) s.bias2[0][tid] = b3[tid];
    } else {
      if (tid < NF) s.W[tid] = W4[tid];
      if (tid == 0) s.bias2[1][0] = b4[0];
    }

    // AGG: feat[d][l*32+f] = tanh(dinv[d]*(sum_e hs[src] + hs[d]) + b); thread = (d, f-quad)
    {
      int dd = tid >> 3, fq = tid & 7;
      const float* bc = s.bias2[l & 1];
      float4 b4q = ld4(&bc[fq * 4]);
      #pragma unroll
      for (int pass = 0; pass < 2; ++pass) {
        int d = dd + pass * 64;
        if (d < NPG) {
          float4 r = ld4(&s.v.hs[d * HSTR + fq * 4]);   // self term
          int p0 = s.ptr[d], p1 = s.ptr[d + 1];
          for (int idx = p0; idx < p1; ++idx) {
            int sc = s.csr[idx];
            float4 hq = ld4(&s.v.hs[sc * HSTR + fq * 4]);
            r.x += hq.x; r.y += hq.y; r.z += hq.z; r.w += hq.w;
          }
          float di = s.dinv[d];
          float4 o;
          o.x = tanh_fast(di * r.x + b4q.x);
          o.y = tanh_fast(di * r.y + b4q.y);
          o.z = tanh_fast(di * r.z + b4q.z);
          o.w = tanh_fast(di * r.w + b4q.w);
          st4(&s.feat[d * FSTR + l * NF + fq * 4], o);
        }
      }
    }
    __syncthreads();
  }

  // ---- layer 4 (1-wide output)
  float* hsf = s.v.hs;  // flat reuse, 100 floats
  if (tid < NPG) {
    float a = 0.f;
    #pragma unroll
    for (int kq = 0; kq < 8; ++kq) {
      float4 a4 = ld4(&s.feat[tid * FSTR + 64 + kq * 4]);
      float4 w4 = ld4(&s.W[kq * 4]);
      a += dot4(a4, w4);
    }
    hsf[tid] = a * s.dinv[tid];
  }
  __syncthreads();
  if (tid < NPG) {
    float r = hsf[tid];
    int p0 = s.ptr[tid], p1 = s.ptr[tid + 1];
    for (int idx = p0; idx < p1; ++idx) r += hsf[s.csr[idx]];
    s.feat[tid * FSTR + 96] = tanh_fast(s.dinv[tid] * r + s.bias2[1][0]);
  }
  __syncthreads();

  // ---- P7: stable top-30 by col 96 descending (rank counting)
  if (tid < NPG) {
    float vv = s.feat[tid * FSTR + 96];
    int rank = 0;
    for (int j = 0; j < NPG; ++j) {
      float vj = s.feat[j * FSTR + 96];
      rank += (vj > vv) || (vj == vv && j < tid);
    }
    if (rank < KP) s.v.r.order[rank] = tid;
  }
  __syncthreads();

  // ---- P8: priors[i][c][e] = pooled[i] . Wcap[c][e]; thread = (i,e); Wcap streamed from L1/L2
  if (tid < KP * OUTL) {
    int i = tid >> 4, e = tid & 15;
    int row = s.v.r.order[i] * FSTR;
    float acc[NC];
    #pragma unroll
    for (int c = 0; c < NC; ++c) acc[c] = 0.f;
    if (WSC) {
      for (int lq = 0; lq < LQ; ++lq) {
        float4 f4 = ld4(&s.feat[row + lq * 4]);
        #pragma unroll
        for (int c = 0; c < NC; ++c) {
          float4 w4 = ld4(capT + ((c * LQ + lq) * OUTL + e) * 4);
          acc[c] += dot4(f4, w4);
        }
      }
      float xl = s.feat[row + 96];
      #pragma unroll
      for (int c = 0; c < NC; ++c) acc[c] += xl * capL[c * OUTL + e];
    } else {
      for (int c = 0; c < NC; ++c) {
        float a = 0.f;
        for (int l = 0; l < INL; ++l) a += s.feat[row + l] * Wcap[(c * OUTL + e) * INL + l];
        acc[c] = a;
      }
    }
    #pragma unroll
    for (int c = 0; c < NC; ++c) s.u.priors[(i * NC + c) * OUTL + e] = acc[c];
  }
  __syncthreads();

  // ---- P9: pr_sq, out init
  if (tid < KP * NC) {
    const float* pr = &s.u.priors[tid * OUTL];
    float a = 0.f;
    #pragma unroll
    for (int eq = 0; eq < 4; ++eq) { float4 p = ld4(pr + eq * 4); a += dot4(p, p); }
    s.v.r.prsq[tid] = a;
  }
  if (tid < NC * OUTL) {
    int c = tid >> 4, e = tid & 15;
    float a = 0.f;
    #pragma unroll
    for (int i = 0; i < KP; ++i) a += s.u.priors[(i * NC + c) * OUTL + e];
    s.v.r.outv[tid] = a * (1.0f / KP);
  }
  __syncthreads();

  // ---- P10: routing (3 barriers per iter)
  for (int it = 0; it < NITER; ++it) {
    if (tid < KP * NC) {
      int c = tid % NC;
      const float* pr = &s.u.priors[tid * OUTL];
      const float* ov = &s.v.r.outv[c * OUTL];
      float xy = 0.f, oq = 0.f;
      #pragma unroll
      for (int eq = 0; eq < 4; ++eq) {
        float4 p = ld4(pr + eq * 4);
        float4 o = ld4(ov + eq * 4);
        xy += dot4(p, o); oq += dot4(o, o);
      }
      s.v.r.simbuf[tid] = xy / (s.v.r.prsq[tid] + oq - xy);
    }
    __syncthreads();
    if (tid < NC) {
      float m = -1e30f;
      #pragma unroll
      for (int i = 0; i < KP; ++i) m = fmaxf(m, s.v.r.simbuf[i * NC + tid]);
      float ss = 0.f;
      #pragma unroll
      for (int i = 0; i < KP; ++i) ss += __expf(s.v.r.simbuf[i * NC + tid] - m);
      s.v.r.smax[tid] = m;
      s.v.r.ssum[tid] = 1.f / ss;
    }
    __syncthreads();
    if (tid < NC * OUTL) {
      int c = tid >> 4, e = tid & 15;
      float m = s.v.r.smax[c], is = s.v.r.ssum[c], a = 0.f;
      #pragma unroll
      for (int i = 0; i < KP; ++i)
        a += __expf(s.v.r.simbuf[i * NC + c] - m) * s.u.priors[(i * NC + c) * OUTL + e];
      s.v.r.outv[tid] = a * is;
    }
    __syncthreads();
  }

  // ---- P11: classes = ||out||
  if (tid < NC) {
    const float* ov = &s.v.r.outv[tid * OUTL];
    float a = 0.f;
    #pragma unroll
    for (int eq = 0; eq < 4; ++eq) { float4 o = ld4(ov + eq * 4); a += dot4(o, o); }
    out[(size_t)g * NC + tid] = sqrtf(a);
  }
}

extern "C" void kernel_launch(void* const* d_in, const int* in_sizes, int n_in,
                              void* d_out, int out_size, void* d_ws, size_t ws_size,
                              hipStream_t stream) {
  const float* x    = (const float*)d_in[0];
  const int*   esrc = (const int*)d_in[1];
  const int*   edst = (const int*)d_in[2];
  const float* W1 = (const float*)d_in[4];
  const float* b1 = (const float*)d_in[5];
  const float* W2 = (const float*)d_in[6];
  const float* b2 = (const float*)d_in[7];
  const float* W3 = (const float*)d_in[8];
  const float* b3 = (const float*)d_in[9];
  const float* W4 = (const float*)d_in[10];
  const float* b4 = (const float*)d_in[11];
  const float* Wcap = (const float*)d_in[12];
  float* outp = (float*)d_out;

  const bool wse = ws_size >= WS_EDGES_BYTES + WS_CAP_BYTES;
  const bool wsc = ws_size >= WS_CAP_BYTES;

  unsigned int* wsE = (unsigned int*)d_ws;
  float* capT = wse ? (float*)((char*)d_ws + WS_EDGES_BYTES) : (float*)d_ws;
  float* capL = capT + WS_CAPT_FLOATS;

  (void)hipFuncSetAttribute((const void*)gcn_caps<true, true>,
                            hipFuncAttributeMaxDynamicSharedMemorySize, (int)sizeof(SMem));
  (void)hipFuncSetAttribute((const void*)gcn_caps<false, true>,
                            hipFuncAttributeMaxDynamicSharedMemorySize, (int)sizeof(SMem));
  (void)hipFuncSetAttribute((const void*)gcn_caps<false, false>,
                            hipFuncAttributeMaxDynamicSharedMemorySize, (int)sizeof(SMem));

  if (wse) {
    prek_edges<<<(EPG / 64) * 16, 256, 0, stream>>>(esrc, edst, wsE);
    prek_cap<<<(WS_CAPT_FLOATS + 255) / 256, 256, 0, stream>>>(Wcap, capT, capL);
    gcn_caps<true, true><<<NGRAPH, NT, sizeof(SMem), stream>>>(
        x, esrc, edst, W1, b1, W2, b2, W3, b3, W4, b4, Wcap, wsE, capT, capL, outp);
  } else if (wsc) {
    prek_cap<<<(WS_CAPT_FLOATS + 255) / 256, 256, 0, stream>>>(Wcap, capT, capL);
    gcn_caps<false, true><<<NGRAPH, NT, sizeof(SMem), stream>>>(
        x, esrc, edst, W1, b1, W2, b2, W3, b3, W4, b4, Wcap, wsE, capT, capL, outp);
  } else {
    gcn_caps<false, false><<<NGRAPH, NT, sizeof(SMem), stream>>>(
        x, esrc, edst, W1, b1, W2, b2, W3, b3, W4, b4, Wcap, wsE, capT, capL, outp);
  }
}